// Round 1
// 95.505 us; speedup vs baseline: 1.0432x; 1.0432x over previous
//
#include <hip/hip_runtime.h>
#include <hip/hip_fp16.h>
#include <math.h>

// K=4, R=16384, kappa=32, NX=3, NF=13, DOUT=64, n=16
#define KR 65536
#define RS 16384
#define KAPPA 32

typedef __attribute__((ext_vector_type(8))) _Float16 f16x8;   // 4 VGPR, 16 B
typedef __attribute__((ext_vector_type(4))) float f32x4;      // mfma 16x16 C/D
typedef __attribute__((ext_vector_type(16))) float f32x16;    // mfma 32x32 C/D

// ---------------------------------------------------------------------------
// Kernel 1: pack P=[X|F] rows to fp16 (32 B/row, 2 MiB total) and H to fp16.
// The 2 MiB Ppack table fits in EVERY XCD's 4 MiB L2 simultaneously, so the
// gather phase is L2-resident by construction — no dependence on the
// blockIdx->XCD dispatch mapping (which the old 8 MiB fp16-Q scheme needed).
// ---------------------------------------------------------------------------
__global__ __launch_bounds__(256) void pack_kernel(
    const float* __restrict__ X, const float* __restrict__ F,
    const float* __restrict__ H, _Float16* __restrict__ Pp,
    _Float16* __restrict__ Hp) {
  const int p = blockIdx.x * 256 + threadIdx.x;  // 256 blocks x 256 = 65536
  const size_t qx = (size_t)p * 3, qf = (size_t)p * 13;
  f16x8 lo, hi;
  lo[0] = (_Float16)X[qx + 0];
  lo[1] = (_Float16)X[qx + 1];
  lo[2] = (_Float16)X[qx + 2];
  #pragma unroll
  for (int j = 0; j < 5; ++j) lo[3 + j] = (_Float16)F[qf + j];
  #pragma unroll
  for (int j = 0; j < 8; ++j) hi[j] = (_Float16)F[qf + 5 + j];
  *(f16x8*)(Pp + (size_t)p * 16 + 0) = lo;
  *(f16x8*)(Pp + (size_t)p * 16 + 8) = hi;

  if (blockIdx.x == 0 && threadIdx.x < 64) {
    const int d = threadIdx.x;
    f16x8 a, b;
    #pragma unroll
    for (int j = 0; j < 8; ++j) {
      a[j] = (_Float16)H[d * 16 + j];
      b[j] = (_Float16)H[d * 16 + 8 + j];
    }
    *(f16x8*)(Hp + d * 16 + 0) = a;
    *(f16x8*)(Hp + d * 16 + 8) = b;
  }
}

// ---------------------------------------------------------------------------
// Kernel 2 (fused): per point, gather 32 fp16 P-rows (32 B each, L2-resident),
// SharedMLP via mfma_f32_32x32x16_f16 (A = 32 nbrs x 16 feats, 2 MFMA/point),
// relu+max over MFMA rows (row-permutation-invariant -> only the verified
// col=lane&31 C-layout matters), then the 32x64 @ 64x64 gamma GEMM as before.
// 2048 blocks x 256 threads, 32 points/block, 8 points/wave.
// ---------------------------------------------------------------------------
__global__ __launch_bounds__(256) void fused_kernel(
    const _Float16* __restrict__ Pp, const _Float16* __restrict__ Hp,
    const int* __restrict__ N, const float* __restrict__ gamma,
    const float* __restrict__ gbias, float* __restrict__ Y) {
  __shared__ _Float16 Gt[64 * 72];  // Gt[e][d] (transposed gamma), 9.2 KB
  __shared__ _Float16 Ml[32 * 72];  // Ml[p][d], 4.6 KB
  __shared__ float Bl[64];

  const int t = threadIdx.x;
  // stage gamma transposed -> fp16 (unchanged from passing baseline)
  #pragma unroll
  for (int ii = 0; ii < 4; ++ii) {
    const int i = t + ii * 256;
    const float4 gv = ((const float4*)gamma)[i];
    const int d = i >> 4, e0 = (i & 15) * 4;
    Gt[(e0 + 0) * 72 + d] = (_Float16)gv.x;
    Gt[(e0 + 1) * 72 + d] = (_Float16)gv.y;
    Gt[(e0 + 2) * 72 + d] = (_Float16)gv.z;
    Gt[(e0 + 3) * 72 + d] = (_Float16)gv.w;
  }
  if (t < 64) Bl[t] = gbias[t];

  const int lane = t & 63, wave = t >> 6;
  const int l31 = lane & 31, hsel = lane >> 5;  // feature-half select

  const int base = blockIdx.x * 32;        // contiguous points; no XCD swizzle
  const int k = blockIdx.x >> 9;           // 512 blocks per k-slice
  const _Float16* Pk = Pp + ((size_t)k * RS) * 16;

  // B-frags: B[k16][col] = H[d][k16]; lane holds d = ct*32+l31, k = hsel*8..+7
  const f16x8 hb0 = *(const f16x8*)(Hp + (0  + l31) * 16 + hsel * 8);
  const f16x8 hb1 = *(const f16x8*)(Hp + (32 + l31) * 16 + hsel * 8);

  // ---- Phase A: 8 points per wave; one dwordx4 gather + 2 MFMA per point ---
  const int p0 = base + wave * 8;
  int idx[8];
  #pragma unroll
  for (int j = 0; j < 8; ++j)  // nbr index for A-row l31 (1 line, broadcast)
    idx[j] = __builtin_nontemporal_load(N + (size_t)(p0 + j) * KAPPA + l31);

  const f32x16 z = {0.f, 0.f, 0.f, 0.f, 0.f, 0.f, 0.f, 0.f,
                    0.f, 0.f, 0.f, 0.f, 0.f, 0.f, 0.f, 0.f};
  #pragma unroll
  for (int j = 0; j < 8; ++j) {
    // A-frag: A[row=l31][k=hsel*8+i] = Ppack[idx[row]][hsel*8+i]
    const f16x8 a = *(const f16x8*)(Pk + (size_t)idx[j] * 16 + hsel * 8);
    const f32x16 c0 = __builtin_amdgcn_mfma_f32_32x32x16_f16(a, hb0, z, 0, 0, 0);
    const f32x16 c1 = __builtin_amdgcn_mfma_f32_32x32x16_f16(a, hb1, z, 0, 0, 0);
    // relu+max over the 16 neighbor-rows this lane holds (order-irrelevant)
    float m0 = fmaxf(
        fmaxf(fmaxf(fmaxf(c0[0], c0[1]), fmaxf(c0[2], c0[3])),
              fmaxf(fmaxf(c0[4], c0[5]), fmaxf(c0[6], c0[7]))),
        fmaxf(fmaxf(fmaxf(c0[8], c0[9]), fmaxf(c0[10], c0[11])),
              fmaxf(fmaxf(c0[12], c0[13]), fmaxf(c0[14], c0[15]))));
    float m1 = fmaxf(
        fmaxf(fmaxf(fmaxf(c1[0], c1[1]), fmaxf(c1[2], c1[3])),
              fmaxf(fmaxf(c1[4], c1[5]), fmaxf(c1[6], c1[7]))),
        fmaxf(fmaxf(fmaxf(c1[8], c1[9]), fmaxf(c1[10], c1[11])),
              fmaxf(fmaxf(c1[12], c1[13]), fmaxf(c1[14], c1[15]))));
    m0 = fmaxf(m0, 0.0f);  // relu folded
    m1 = fmaxf(m1, 0.0f);
    // other 16 rows live in the lane^32 partner
    m0 = fmaxf(m0, __shfl_xor(m0, 32, 64));
    m1 = fmaxf(m1, __shfl_xor(m1, 32, 64));
    // lane writes d = hsel*32 + l31 = lane
    const float ms = hsel ? m1 : m0;
    Ml[(wave * 8 + j) * 72 + lane] = (_Float16)ms;  // 128 B row, 2-way free
  }
  __syncthreads();

  // ---- Phase B: C(32x64) = Ml @ Gt^T via mfma 16x16x32 (unchanged) ----
  const int ln15 = lane & 15, quad = lane >> 4;
  const int rt = wave & 1, ct = wave >> 1;
  f32x4 acc[2] = {{0.f, 0.f, 0.f, 0.f}, {0.f, 0.f, 0.f, 0.f}};
  #pragma unroll
  for (int ks = 0; ks < 2; ++ks) {
    const f16x8 af = *(const f16x8*)(Ml + (rt * 16 + ln15) * 72 + ks * 32 + quad * 8);
    #pragma unroll
    for (int nt = 0; nt < 2; ++nt) {
      const f16x8 bf = *(const f16x8*)(Gt + (ct * 32 + nt * 16 + ln15) * 72 + ks * 32 + quad * 8);
      acc[nt] = __builtin_amdgcn_mfma_f32_16x16x32_f16(af, bf, acc[nt], 0, 0, 0);
    }
  }

  // epilogue: C/D layout col=lane&15, row=quad*4+reg; streaming Y stores
  #pragma unroll
  for (int nt = 0; nt < 2; ++nt) {
    const float bv = Bl[ct * 32 + nt * 16 + ln15];
    #pragma unroll
    for (int r = 0; r < 4; ++r) {
      const float y = fmaxf(acc[nt][r] + bv, 0.0f);
      __builtin_nontemporal_store(
          y, Y + (size_t)(base + rt * 16 + quad * 4 + r) * 64 + ct * 32 + nt * 16 + ln15);
    }
  }
}

extern "C" void kernel_launch(void* const* d_in, const int* in_sizes, int n_in,
                              void* d_out, int out_size, void* d_ws, size_t ws_size,
                              hipStream_t stream) {
  const float* X  = (const float*)d_in[0];
  const float* F  = (const float*)d_in[1];
  const int*   N  = (const int*)d_in[2];
  const float* H  = (const float*)d_in[3];
  const float* G  = (const float*)d_in[4];
  const float* Gb = (const float*)d_in[5];
  float* Y = (float*)d_out;
  _Float16* Pp = (_Float16*)d_ws;          // KR*16*2 B = 2 MiB
  _Float16* Hp = Pp + (size_t)KR * 16;     // 64*16*2 B = 2 KiB

  pack_kernel<<<256, 256, 0, stream>>>(X, F, H, Pp, Hp);
  fused_kernel<<<2048, 256, 0, stream>>>(Pp, Hp, N, G, Gb, Y);
}

// Round 2
// 94.372 us; speedup vs baseline: 1.0558x; 1.0120x over previous
//
#include <hip/hip_runtime.h>
#include <hip/hip_fp16.h>
#include <math.h>

// K=4, R=16384, kappa=32, NX=3, NF=13, DOUT=64, n=16
#define KR 65536
#define RS 16384
#define KAPPA 32

typedef __attribute__((ext_vector_type(8))) _Float16 f16x8;   // 4 VGPR, 16 B
typedef __attribute__((ext_vector_type(4))) float f32x4;      // mfma 16x16 C/D
typedef __attribute__((ext_vector_type(16))) float f32x16;    // mfma 32x32 C/D

// ---------------------------------------------------------------------------
// Kernel 1: pack P=[X|F] rows to fp16 (32 B/row, 2 MiB total), H to fp16,
// and gamma -> fp16 transposed Gp[e][d] (8 KB, packed 64x64) so fused blocks
// stage it with 2 b128 copies/thread instead of 16 KB fp32 + 1024 converts.
// ---------------------------------------------------------------------------
__global__ __launch_bounds__(256) void pack_kernel(
    const float* __restrict__ X, const float* __restrict__ F,
    const float* __restrict__ H, const float* __restrict__ gamma,
    _Float16* __restrict__ Pp, _Float16* __restrict__ Hp,
    _Float16* __restrict__ Gp) {
  const int p = blockIdx.x * 256 + threadIdx.x;  // 256 blocks x 256 = 65536
  const size_t qx = (size_t)p * 3, qf = (size_t)p * 13;
  f16x8 lo, hi;
  lo[0] = (_Float16)X[qx + 0];
  lo[1] = (_Float16)X[qx + 1];
  lo[2] = (_Float16)X[qx + 2];
  #pragma unroll
  for (int j = 0; j < 5; ++j) lo[3 + j] = (_Float16)F[qf + j];
  #pragma unroll
  for (int j = 0; j < 8; ++j) hi[j] = (_Float16)F[qf + 5 + j];
  *(f16x8*)(Pp + (size_t)p * 16 + 0) = lo;
  *(f16x8*)(Pp + (size_t)p * 16 + 8) = hi;

  if (blockIdx.x == 0) {
    if (threadIdx.x < 64) {
      const int d = threadIdx.x;
      f16x8 a, b;
      #pragma unroll
      for (int j = 0; j < 8; ++j) {
        a[j] = (_Float16)H[d * 16 + j];
        b[j] = (_Float16)H[d * 16 + 8 + j];
      }
      *(f16x8*)(Hp + d * 16 + 0) = a;
      *(f16x8*)(Hp + d * 16 + 8) = b;
    }
    // gamma[d][e] -> Gp[e*64+d], fp16 (same rounding the fused prologue did)
    for (int i = threadIdx.x; i < 4096; i += 256) {
      const int d = i >> 6, e = i & 63;   // coalesced gamma reads
      Gp[e * 64 + d] = (_Float16)gamma[i];
    }
  }
}

__device__ __forceinline__ float max16(const f32x16 c) {
  // 3-ary nests -> v_max3_f32 fusion: ~8 ops instead of 15
  const float a = fmaxf(fmaxf(c[0], c[1]), c[2]);
  const float b = fmaxf(fmaxf(c[3], c[4]), c[5]);
  const float d = fmaxf(fmaxf(c[6], c[7]), c[8]);
  const float e = fmaxf(fmaxf(c[9], c[10]), c[11]);
  const float f = fmaxf(fmaxf(c[12], c[13]), c[14]);
  return fmaxf(fmaxf(fmaxf(a, b), d), fmaxf(fmaxf(e, f), c[15]));
}

// ---------------------------------------------------------------------------
// Kernel 2 (fused): 1024 blocks x 256 threads, 64 points/block (was 32) to
// halve per-block fixed costs. Per point: gather 32 fp16 P-rows (L2-resident
// 2 MiB table), SharedMLP via mfma_f32_32x32x16_f16 (2 MFMA/point),
// relu+max over rows, then the 64x64 @ 64x64 gamma GEMM.
// ---------------------------------------------------------------------------
__global__ __launch_bounds__(256) void fused_kernel(
    const _Float16* __restrict__ Pp, const _Float16* __restrict__ Hp,
    const _Float16* __restrict__ Gp, const int* __restrict__ N,
    const float* __restrict__ gbias, float* __restrict__ Y) {
  __shared__ _Float16 Gt[64 * 72];  // Gt[e][d], 9.2 KB
  __shared__ _Float16 Ml[64 * 72];  // Ml[p][d], 9.2 KB
  __shared__ float Bl[64];

  const int t = threadIdx.x;
  // stage pre-packed fp16 gamma: 512 b128 chunks, 2 per thread
  #pragma unroll
  for (int u = 0; u < 2; ++u) {
    const int ci = t * 2 + u;                       // [0,512)
    const f16x8 g = *(const f16x8*)(Gp + ci * 8);   // coalesced 16 B
    *(f16x8*)(Gt + (ci >> 3) * 72 + (ci & 7) * 8) = g;
  }
  if (t < 64) Bl[t] = gbias[t];

  const int lane = t & 63, wave = t >> 6;
  const int l31 = lane & 31, hsel = lane >> 5;  // feature-half select

  const int base = blockIdx.x * 64;
  const int k = blockIdx.x >> 8;                // 256 blocks per k-slice
  const _Float16* Pk = Pp + ((size_t)k * RS) * 16;

  // B-frags: lane holds d = l31 (+32), k = hsel*8..+7
  const f16x8 hb0 = *(const f16x8*)(Hp + (0  + l31) * 16 + hsel * 8);
  const f16x8 hb1 = *(const f16x8*)(Hp + (32 + l31) * 16 + hsel * 8);

  const f32x16 z = {0.f, 0.f, 0.f, 0.f, 0.f, 0.f, 0.f, 0.f,
                    0.f, 0.f, 0.f, 0.f, 0.f, 0.f, 0.f, 0.f};

  // ---- Phase A: 16 points per wave, in two 8-point halves (caps VGPRs) ----
  #pragma unroll 1
  for (int half = 0; half < 2; ++half) {
    const int p0 = base + wave * 16 + half * 8;
    int idx[8];
    #pragma unroll
    for (int j = 0; j < 8; ++j)  // nbr index for A-row l31 (1 line, broadcast)
      idx[j] = __builtin_nontemporal_load(N + (size_t)(p0 + j) * KAPPA + l31);

    #pragma unroll
    for (int j = 0; j < 8; ++j) {
      // A-frag: A[row=l31][k=hsel*8+i] = Ppack[idx[row]][hsel*8+i]
      const f16x8 a = *(const f16x8*)(Pk + (size_t)idx[j] * 16 + hsel * 8);
      const f32x16 c0 = __builtin_amdgcn_mfma_f32_32x32x16_f16(a, hb0, z, 0, 0, 0);
      const f32x16 c1 = __builtin_amdgcn_mfma_f32_32x32x16_f16(a, hb1, z, 0, 0, 0);
      // relu+max over the 16 neighbor-rows this lane holds (order-irrelevant)
      float m0 = fmaxf(max16(c0), 0.0f);
      float m1 = fmaxf(max16(c1), 0.0f);
      // other 16 rows live in the lane^32 partner
      m0 = fmaxf(m0, __shfl_xor(m0, 32, 64));
      m1 = fmaxf(m1, __shfl_xor(m1, 32, 64));
      // lane writes d = hsel*32 + l31 = lane
      Ml[(wave * 16 + half * 8 + j) * 72 + lane] = (_Float16)(hsel ? m1 : m0);
    }
  }
  __syncthreads();

  // ---- Phase B: C(64x64) = Ml @ Gt^T; wave w owns rows w*16..+15 ----
  const int ln15 = lane & 15, quad = lane >> 4;
  f32x4 acc[4] = {{0.f, 0.f, 0.f, 0.f}, {0.f, 0.f, 0.f, 0.f},
                  {0.f, 0.f, 0.f, 0.f}, {0.f, 0.f, 0.f, 0.f}};
  #pragma unroll
  for (int ks = 0; ks < 2; ++ks) {
    const f16x8 af = *(const f16x8*)(Ml + (wave * 16 + ln15) * 72 + ks * 32 + quad * 8);
    #pragma unroll
    for (int nt = 0; nt < 4; ++nt) {
      const f16x8 bf = *(const f16x8*)(Gt + (nt * 16 + ln15) * 72 + ks * 32 + quad * 8);
      acc[nt] = __builtin_amdgcn_mfma_f32_16x16x32_f16(af, bf, acc[nt], 0, 0, 0);
    }
  }

  // epilogue: C/D layout col=lane&15, row=quad*4+reg; streaming Y stores
  #pragma unroll
  for (int nt = 0; nt < 4; ++nt) {
    const float bv = Bl[nt * 16 + ln15];
    #pragma unroll
    for (int r = 0; r < 4; ++r) {
      const float y = fmaxf(acc[nt][r] + bv, 0.0f);
      __builtin_nontemporal_store(
          y, Y + (size_t)(base + wave * 16 + quad * 4 + r) * 64 + nt * 16 + ln15);
    }
  }
}

extern "C" void kernel_launch(void* const* d_in, const int* in_sizes, int n_in,
                              void* d_out, int out_size, void* d_ws, size_t ws_size,
                              hipStream_t stream) {
  const float* X  = (const float*)d_in[0];
  const float* F  = (const float*)d_in[1];
  const int*   N  = (const int*)d_in[2];
  const float* H  = (const float*)d_in[3];
  const float* G  = (const float*)d_in[4];
  const float* Gb = (const float*)d_in[5];
  float* Y = (float*)d_out;
  _Float16* Pp = (_Float16*)d_ws;          // KR*16*2 B = 2 MiB
  _Float16* Hp = Pp + (size_t)KR * 16;     // 2 KiB
  _Float16* Gp = Hp + 64 * 16;             // 8 KiB

  pack_kernel<<<256, 256, 0, stream>>>(X, F, H, G, Pp, Hp, Gp);
  fused_kernel<<<1024, 256, 0, stream>>>(Pp, Hp, Gp, N, Gb, Y);
}